// Round 14
// baseline (304.622 us; speedup 1.0000x reference)
//
#include <hip/hip_runtime.h>
#include <hip/hip_bf16.h>

// Grouped conv2d as implicit GEMM per group:
//   out[b*64+co][h][w] = sum_{ci,kh,kw} W[b*64+co][ci][kh][kw] * x[b*64+ci][h+kh-1][w+kw-1]
// bf16 MFMA (16x16x32), fp32 accumulate.
//
// R14 = R13's VMEM-silent compute + R10's max-concurrency gload_lds staging,
// made LDS-feasible by ONE BIG BLOCK PER CU (157.3KB LDS, 512 thr, TILE_H=8):
//  - analysis: kernel is ~85% memory-movement; delivered ~13 B/cyc/CU vs ~56
//    available -> concurrency-limited (Little's law). R13 register ping-pong
//    keeps ~4KB/wave in flight; this keeps ~12KB/wave fire-and-forget.
//  - ALL staging via global_load_lds (x bulk -> fp32 scratch, af -> afs);
//    zero staging registers (R5/R6/R9/R12 spill law respected).
//  - compute reads ONLY LDS (afs + xs) -> issuing next-phase gloads during
//    compute never stalls it (R10's poison removed by R13's afs).
//  - timeline: af0+x0 -> sync -> cvt0 -> sync -> [x1 || comp0] -> sync ->
//              [af1 || cvt1] -> sync -> comp1 -> epilogue.

typedef __bf16 bf16x8 __attribute__((ext_vector_type(8)));
typedef float  f32x4  __attribute__((ext_vector_type(4)));

#define NB 32
#define NH 256
#define NW 256
#define TILE_H 8
#define TILE_W 64
#define XROWS 10    // TILE_H + 2 (halo)
#define XCOLS 66
#define HWSZ ((size_t)NH * NW)

__device__ __forceinline__ void gload16(const float* g, float* lds) {
    __builtin_amdgcn_global_load_lds(
        (const __attribute__((address_space(1))) unsigned int*)g,
        (__attribute__((address_space(3))) unsigned int*)lds, 16, 0, 0);
}

// ---------------------------------------------------------------------------
// Repack weights into MFMA A-fragment order:
//   pk[((b*9+tap)*4+mt)*2+kc][lane][j]  (bf16, 16B per lane)
// value = W[b*64 + mt*16 + (lane&15)][kc*32 + (lane>>4)*8 + j][tap]
// ---------------------------------------------------------------------------
__global__ void repack_weights_kernel(const float* __restrict__ wsrc,
                                      __bf16* __restrict__ pk) {
    int t = blockIdx.x * blockDim.x + threadIdx.x;
    if (t >= NB * 9 * 4 * 2 * 64) return;
    int lane = t & 63;
    int r = t >> 6;
    int kc = r & 1;  r >>= 1;
    int mt = r & 3;  r >>= 2;
    int tap = r % 9;
    int b   = r / 9;
    int co  = b * 64 + mt * 16 + (lane & 15);
    int ci0 = kc * 32 + (lane >> 4) * 8;
    bf16x8 v;
#pragma unroll
    for (int j = 0; j < 8; ++j) {
        v[j] = (__bf16)wsrc[(co * 64 + ci0 + j) * 9 + tap];
    }
    *reinterpret_cast<bf16x8*>(pk + (size_t)t * 8) = v;
}

// ---------------------------------------------------------------------------
// Main conv kernel. Block = (group b, 8 output rows, 64 cols), 8 waves,
// 1 block/CU (157.3KB LDS). Wave wid = output row h0+wid, all 64 co.
// scratch: [10][32ci][64w] fp32 (gload_lds, linear chunks).
// xs: [r][c][32] bf16, octet o of col c at 8*(o ^ ((c>>1)&3)).
// afs: 36 frags x 512 bf16 lane-linear, refilled per kc phase.
// ---------------------------------------------------------------------------
__launch_bounds__(512)
__global__ void conv_mfma_kernel(const float* __restrict__ x,
                                 const __bf16* __restrict__ pk,
                                 float* __restrict__ out) {
    __shared__ __align__(16) __bf16 xs[XROWS * XCOLS * 32];    // 42240 B
    __shared__ __align__(16) __bf16 afs[36 * 512];             // 36864 B
    __shared__ __align__(16) float  scratch[XROWS * 32 * 64];  // 81920 B

    // XCD-aware bijective swizzle: 4096 blocks, 8 XCDs -> 512-chunk per XCD
    const int orig = blockIdx.x;
    const int wg   = (orig & 7) * 512 + (orig >> 3);
    const int b    = wg >> 7;            // 0..31
    const int by   = (wg >> 2) & 31;     // 0..31
    const int bx   = wg & 3;             // 0..3
    const int h0   = by * TILE_H;
    const int w0   = bx * TILE_W;

    const int tid  = threadIdx.x;
    const int wid  = tid >> 6;           // 0..7
    const int lane = tid & 63;
    const int nl   = lane & 15;
    const int kgrp = lane >> 4;          // 0..3

    const char* pkb = (const char*)(pk + (size_t)b * 9 * 4096);

    // ---- af copy for phase kcv: frags f == wid (mod 8), zero registers ----
    auto issue_af = [&](int kcv) {
#pragma unroll
        for (int i = 0; i < 5; ++i) {
            const int f = wid + i * 8;        // 0..39, skip >=36
            if (f < 36) {
                const int tp = f >> 2;
                const int mt = f & 3;
                const float* src = (const float*)(pkb + tp * 8192
                                                  + (mt * 2 + kcv) * 1024 + lane * 16);
                gload16(src, (float*)((char*)afs + f * 1024));
            }
        }
    };

    // ---- x bulk gloads for phase kcv: 80 chunks, 10/wave, zero registers ----
    auto issue_x = [&](int kcv) {
#pragma unroll
        for (int m = 0; m < 10; ++m) {
            const int I  = wid * 10 + m;     // 0..79
            const int r  = I >> 3;           // 0..9
            const int cb = I & 7;            // 4-ci block
            const int hh = h0 - 1 + r;
            const int hc = min(max(hh, 0), NH - 1);
            const float* src = x
                + ((size_t)(b * 64 + kcv * 32 + cb * 4 + (lane >> 4)) * NH + hc) * NW
                + w0 + (lane & 15) * 4;
            gload16(src, scratch + (r * 32 + cb * 4) * 64);
        }
    };

    // halo constants (threads 0..79: c=64+? -> cols 0 and 65)
    const int hr    = tid >> 3;              // 0..9
    const int hside = (tid >> 2) & 1;        // 0 -> col 0 (w0-1), 1 -> col 65 (w0+64)
    const int hoct  = tid & 3;
    const int hwv   = hside ? (w0 + 64) : (w0 - 1);
    float hreg[8];
    bool  hz = false;

    auto issue_halo = [&](int kcv) {
        if (tid < 80) {
            const int hh = h0 - 1 + hr;
            hz = (hwv < 0) || (hwv > NW - 1) || (hh < 0) || (hh > NH - 1);
            const int wc2 = min(max(hwv, 0), NW - 1);
            const int hc2 = min(max(hh, 0), NH - 1);
            const float* s = x + ((size_t)(b * 64 + kcv * 32 + hoct * 8) * NH + hc2) * NW + wc2;
#pragma unroll
            for (int j = 0; j < 8; ++j) hreg[j] = s[j * HWSZ];
        }
    };

    // ---- cvt: scratch fp32 -> xs bf16 (verified swizzled layout) ----
    const int c = lane;                      // main col -> xs col c+1
    auto cvt = [&]() {
#pragma unroll
        for (int k = 0; k < 5; ++k) {
            const int p   = wid * 5 + k;     // 0..39
            const int rr  = p >> 2;
            const int oct = p & 3;
            const int hh  = h0 - 1 + rr;
            const bool z  = (hh < 0) || (hh > NH - 1);
            float v[8];
#pragma unroll
            for (int j = 0; j < 8; ++j)
                v[j] = scratch[(rr * 32 + oct * 8 + j) * 64 + c];
            bf16x8 o8;
#pragma unroll
            for (int j = 0; j < 8; ++j) o8[j] = z ? (__bf16)0.f : (__bf16)v[j];
            const int cc = c + 1;
            *reinterpret_cast<bf16x8*>(
                xs + (rr * XCOLS + cc) * 32 + ((oct ^ ((cc >> 1) & 3)) * 8)) = o8;
        }
        if (tid < 80) {
            bf16x8 o8;
#pragma unroll
            for (int j = 0; j < 8; ++j) o8[j] = hz ? (__bf16)0.f : (__bf16)hreg[j];
            const int cc = hside ? 65 : 0;   // slot(0)=slot(65)=0 -> pos = hoct
            *reinterpret_cast<bf16x8*>(xs + (hr * XCOLS + cc) * 32 + hoct * 8) = o8;
        }
    };

    f32x4 acc[4][4];   // [mt][q]
#pragma unroll
    for (int mt = 0; mt < 4; ++mt)
#pragma unroll
        for (int q = 0; q < 4; ++q)
            acc[mt][q] = (f32x4){0.f, 0.f, 0.f, 0.f};

    // ---- compute one kc phase: 9 taps, fully VMEM-silent ----
    auto compute = [&]() {
#pragma unroll
        for (int tap = 0; tap < 9; ++tap) {
            bf16x8 afr[4];
#pragma unroll
            for (int mt = 0; mt < 4; ++mt)
                afr[mt] = *reinterpret_cast<const bf16x8*>(
                    afs + (tap * 4 + mt) * 512 + lane * 8);
            const int kh = tap / 3;
            const int kw = tap - kh * 3;
            const int rowbase = (wid + kh) * XCOLS;
#pragma unroll
            for (int q = 0; q < 4; ++q) {
                const int cc   = q * 16 + nl + kw;          // 0..65
                const int slot = (cc >> 1) & 3;
                bf16x8 bfv = *reinterpret_cast<const bf16x8*>(
                    xs + (rowbase + cc) * 32 + ((kgrp ^ slot) * 8));
#pragma unroll
                for (int mt = 0; mt < 4; ++mt)
                    acc[mt][q] = __builtin_amdgcn_mfma_f32_16x16x32_bf16(
                        afr[mt], bfv, acc[mt][q], 0, 0, 0);
            }
        }
    };

    // ---- driver ----
    issue_af(0);
    issue_x(0);
    issue_halo(0);
    __syncthreads();          // drain: afs + scratch ready
    cvt();
    __syncthreads();          // xs ready; scratch free
    issue_x(1);               // fire-and-forget, rides under compute(0)
    issue_halo(1);
    compute();                // VMEM-silent
    __syncthreads();          // drain x(1); afs free (compute(0) done)
    issue_af(1);              // rides under cvt(1)
    cvt();
    __syncthreads();          // drain af(1); xs ready
    compute();

    // ---- epilogue: D lane layout col=lane&15, row=(lane>>4)*4+reg ----
    const int mrow = kgrp * 4;
    const int h = h0 + wid;
#pragma unroll
    for (int mt = 0; mt < 4; ++mt) {
#pragma unroll
        for (int q = 0; q < 4; ++q) {
            const int ww = w0 + q * 16 + nl;
#pragma unroll
            for (int rg = 0; rg < 4; ++rg) {
                const int co = mt * 16 + mrow + rg;
                out[((size_t)(b * 64 + co) * NH + h) * NW + ww] = acc[mt][q][rg];
            }
        }
    }
}

extern "C" void kernel_launch(void* const* d_in, const int* in_sizes, int n_in,
                              void* d_out, int out_size, void* d_ws, size_t ws_size,
                              hipStream_t stream) {
    const float* x = (const float*)d_in[0];     // [1, 32*64, 256, 256] fp32
    const float* w = (const float*)d_in[1];     // [2048, 64, 3, 3] fp32
    float* out = (float*)d_out;                 // [1, 2048, 256, 256] fp32
    __bf16* pk = (__bf16*)d_ws;                 // 2.25 MB repacked bf16 weights

    {
        int total = NB * 9 * 4 * 2 * 64;        // 147456
        int blk = 256;
        int grid = (total + blk - 1) / blk;     // 576
        hipLaunchKernelGGL(repack_weights_kernel, dim3(grid), dim3(blk), 0, stream,
                           w, pk);
    }
    {
        dim3 grid(4096);                        // 32b x 32by x 4bx, swizzled
        hipLaunchKernelGGL(conv_mfma_kernel, grid, dim3(512), 0, stream,
                           x, pk, out);
    }
}